// Round 4
// baseline (336.490 us; speedup 1.0000x reference)
//
#include <hip/hip_runtime.h>

#define VSZ 192   // floats of per-view data in workspace (186 used, padded)

// ---------------- SH basis (degree 4, 25 components), float ----------------
__device__ __forceinline__ void sh_basis25(float x, float y, float z, float* Y) {
    float x2 = x * x, y2 = y * y, z2 = z * z;
    Y[0]  = 0.2820947918f;
    Y[1]  = 0.4886025119f * y;
    Y[2]  = 0.4886025119f * z;
    Y[3]  = 0.4886025119f * x;
    Y[4]  = 1.0925484306f * x * y;
    Y[5]  = 1.0925484306f * y * z;
    Y[6]  = 0.3153915653f * (3.0f * z2 - 1.0f);
    Y[7]  = 1.0925484306f * x * z;
    Y[8]  = 0.5462742153f * (x2 - y2);
    Y[9]  = 0.5900435899f * y * (3.0f * x2 - y2);
    Y[10] = 2.8906114426f * x * y * z;
    Y[11] = 0.4570457995f * y * (5.0f * z2 - 1.0f);
    Y[12] = 0.3731763326f * z * (5.0f * z2 - 3.0f);
    Y[13] = 0.4570457995f * x * (5.0f * z2 - 1.0f);
    Y[14] = 1.4453057213f * z * (x2 - y2);
    Y[15] = 0.5900435899f * x * (x2 - 3.0f * y2);
    Y[16] = 2.5033429418f * x * y * (x2 - y2);
    Y[17] = 1.7701307698f * y * z * (3.0f * x2 - y2);
    Y[18] = 0.9461746958f * x * y * (7.0f * z2 - 1.0f);
    Y[19] = 0.6690465436f * y * z * (7.0f * z2 - 3.0f);
    Y[20] = 0.1057855469f * (35.0f * z2 * z2 - 30.0f * z2 + 3.0f);
    Y[21] = 0.6690465436f * x * z * (7.0f * z2 - 3.0f);
    Y[22] = 0.4730873479f * (x2 - y2) * (7.0f * z2 - 1.0f);
    Y[23] = 1.7701307698f * x * z * (x2 - 3.0f * y2);
    Y[24] = 0.6258357354f * (x2 * x2 - 6.0f * x2 * y2 + y2 * y2);
}

// Per-view data layout (floats):
// [0:9)   R_c2w row-major
// [9:12)  cam_o
// [12:21) Kinv row-major
// [21]    scale_adj
// [22:31) D1 (3x3)   [31:56) D2 (5x5)   [56:105) D3 (7x7)   [105:186) D4 (9x9)
//
// Ring sample set per band l: 2l+1 equally spaced phases at z0=0.5.
// Discrete trig orthogonality over the ring is exact ->
// Binv[m,s] = B[s,m] / sum_s' B[s',m]^2 (no matrix inversion).
__global__ __launch_bounds__(64) void setup_kernel(
        const float* __restrict__ ext,
        const float* __restrict__ intr,
        const int* __restrict__ ph,
        const int* __restrict__ pw,
        float* __restrict__ vdg) {
    __shared__ float Bs[24][9];     // unrotated basis rows (sample-major)
    __shared__ float Yrs[24][9];    // rotated basis rows
    __shared__ float normInv[24];   // per-(l,m) 1/norm

    int bv = blockIdx.x;
    int tid = threadIdx.x;
    const float* E = ext + bv * 16;
    const float* K = intr + bv * 9;
    float* o = vdg + bv * VSZ;

    const float z0 = 0.5f, r0 = 0.8660254037844386f;  // sqrt(3)/2
    const float TWO_PI = 6.283185307179586f;

    if (tid < 24) {
        int l, base;
        if      (tid < 3)  { l = 1; base = 0;  }
        else if (tid < 8)  { l = 2; base = 3;  }
        else if (tid < 15) { l = 3; base = 8;  }
        else               { l = 4; base = 15; }
        int n  = 2 * l + 1;
        int si = tid - base;
        int lo = l * l;
        float phs = 0.4f + TWO_PI * (float)si / (float)n;
        float sx = r0 * cosf(phs), sy = r0 * sinf(phs), sz = z0;
        float Y[25];
        sh_basis25(sx, sy, sz, Y);
        for (int k = 0; k < n; k++) Bs[tid][k] = Y[lo + k];
        float dx = E[0] * sx + E[1] * sy + E[2]  * sz;
        float dy = E[4] * sx + E[5] * sy + E[6]  * sz;
        float dz = E[8] * sx + E[9] * sy + E[10] * sz;
        sh_basis25(dx, dy, dz, Y);
        for (int k = 0; k < n; k++) Yrs[tid][k] = Y[lo + k];
    }
    __syncthreads();

    if (tid < 24) {
        int l, base;
        if      (tid < 3)  { l = 1; base = 0;  }
        else if (tid < 8)  { l = 2; base = 3;  }
        else if (tid < 15) { l = 3; base = 8;  }
        else               { l = 4; base = 15; }
        int n = 2 * l + 1;
        int m = tid - base;
        float acc = 0.f;
        for (int s = 0; s < n; s++) { float v = Bs[base + s][m]; acc += v * v; }
        normInv[tid] = 1.0f / acc;
    }
    __syncthreads();

    const int dofs[5] = {0, 22, 31, 56, 105};
    for (int e = tid; e < 164; e += 64) {
        int l, ebase, sbase;
        if      (e < 9)  { l = 1; ebase = 0;  sbase = 0;  }
        else if (e < 34) { l = 2; ebase = 9;  sbase = 3;  }
        else if (e < 83) { l = 3; ebase = 34; sbase = 8;  }
        else             { l = 4; ebase = 83; sbase = 15; }
        int n = 2 * l + 1;
        int el = e - ebase;
        int m = el / n, k = el % n;
        float acc = 0.f;
        for (int s = 0; s < n; s++) acc += Yrs[sbase + s][k] * Bs[sbase + s][m];
        o[dofs[l] + m * n + k] = acc * normInv[sbase + m];
    }

    if (tid == 0) {
        float Rw2c[3][3], Rc2w[3][3], t[3];
        for (int i = 0; i < 3; i++) {
            for (int j = 0; j < 3; j++) Rw2c[i][j] = E[i * 4 + j];
            t[i] = E[i * 4 + 3];
        }
        for (int i = 0; i < 3; i++)
            for (int j = 0; j < 3; j++) Rc2w[i][j] = Rw2c[j][i];
        for (int i = 0; i < 3; i++)
            for (int j = 0; j < 3; j++) o[i * 3 + j] = Rc2w[i][j];
        for (int i = 0; i < 3; i++) {
            float s = 0.f;
            for (int j = 0; j < 3; j++) s += Rc2w[i][j] * t[j];
            o[9 + i] = -s;
        }
        float a = K[0], b = K[1], c = K[2], d = K[3], e = K[4], f = K[5],
              g = K[6], h = K[7], ii = K[8];
        float det = a * (e * ii - f * h) - b * (d * ii - f * g) + c * (d * h - e * g);
        float id = 1.0f / det;
        o[12 + 0] = (e * ii - f * h) * id; o[12 + 1] = (c * h - b * ii) * id; o[12 + 2] = (b * f - c * e) * id;
        o[12 + 3] = (f * g - d * ii) * id; o[12 + 4] = (a * ii - c * g) * id; o[12 + 5] = (c * d - a * f) * id;
        o[12 + 6] = (d * h - e * g) * id; o[12 + 7] = (b * g - a * h) * id; o[12 + 8] = (a * e - b * d) * id;
        float det2 = a * e - b * d;
        float i00 = e / det2, i01 = -b / det2, i10 = -d / det2, i11 = a / det2;
        float ps0 = 1.0f / (float)(*pw), ps1 = 1.0f / (float)(*ph);
        o[21] = 0.1f * ((i00 + i10) * ps0 + (i01 + i11) * ps1);
    }
}

template <int NB>
__device__ __forceinline__ void apply_D(const float* __restrict__ D,
                                        const float* __restrict__ si,
                                        float* __restrict__ so) {
#pragma unroll
    for (int m = 0; m < NB; m++) {
        float acc = 0.f;
#pragma unroll
        for (int k = 0; k < NB; k++) acc += D[m * NB + k] * si[k];
        so[m] = acc;
    }
}

// One thread per gaussian, direct (unstaged) global reads.
// Record is 82 floats; base byte offset 328*g is 8B-aligned -> float2 loads.
__global__ __launch_bounds__(256, 4) void adapter_kernel(
    const float* __restrict__ pg, const float* __restrict__ pc,
    const float* __restrict__ ops, const float* __restrict__ deps,
    const float* __restrict__ vdg, float* __restrict__ out,
    int R, long long N)
{
    __shared__ float vd[VSZ];
    int bv = blockIdx.y;
    for (int i = threadIdx.x; i < 186; i += 256) vd[i] = vdg[bv * VSZ + i];
    __syncthreads();

    int r = blockIdx.x * 256 + threadIdx.x;
    if (r >= R) return;
    long long g = (long long)bv * R + r;

    const float*  rec  = pg + g * 82;
    const float2* rec2 = (const float2*)rec;

    float depth = deps[g];
    float opac  = ops[g];
    float2 pxy  = ((const float2*)pc)[g];
    float px = pxy.x, py = pxy.y;

    float2 v01 = rec2[0], v23 = rec2[1], v45 = rec2[2];
    float  v6  = rec[6];

    // --- scales ---
    float sadj = vd[21];
    float sraw[3] = {v01.x, v01.y, v23.x};
    float sc[3];
#pragma unroll
    for (int i = 0; i < 3; i++) {
        float sg = 1.0f / (1.0f + expf(-sraw[i]));
        sc[i] = (0.01f + 99.99f * sg) * depth * sadj;
    }

    // --- quats ---
    float qw = v23.y, qx = v45.x, qy = v45.y, qz = v6;
    float qn = rsqrtf(qw * qw + qx * qx + qy * qy + qz * qz);
    qw *= qn; qx *= qn; qy *= qn; qz *= qn;
    float Rq[3][3];
    Rq[0][0] = 1.f - 2.f * (qy * qy + qz * qz);
    Rq[0][1] = 2.f * (qx * qy - qw * qz);
    Rq[0][2] = 2.f * (qx * qz + qw * qy);
    Rq[1][0] = 2.f * (qx * qy + qw * qz);
    Rq[1][1] = 1.f - 2.f * (qx * qx + qz * qz);
    Rq[1][2] = 2.f * (qy * qz - qw * qx);
    Rq[2][0] = 2.f * (qx * qz - qw * qy);
    Rq[2][1] = 2.f * (qy * qz + qw * qx);
    Rq[2][2] = 1.f - 2.f * (qx * qx + qy * qy);

    float Rc[3][3];
#pragma unroll
    for (int i = 0; i < 3; i++)
#pragma unroll
        for (int j = 0; j < 3; j++) Rc[i][j] = vd[i * 3 + j];

    // A = Rc2w @ Rq ; cov = A diag(s^2) A^T
    float A[3][3];
#pragma unroll
    for (int i = 0; i < 3; i++)
#pragma unroll
        for (int k = 0; k < 3; k++)
            A[i][k] = Rc[i][0] * Rq[0][k] + Rc[i][1] * Rq[1][k] + Rc[i][2] * Rq[2][k];
    float s2[3] = {sc[0] * sc[0], sc[1] * sc[1], sc[2] * sc[2]};
    float cov[3][3];
#pragma unroll
    for (int i = 0; i < 3; i++)
#pragma unroll
        for (int j = 0; j < 3; j++)
            cov[i][j] = A[i][0] * s2[0] * A[j][0] + A[i][1] * s2[1] * A[j][1] + A[i][2] * s2[2] * A[j][2];

    // --- ray / means ---
    float dx = vd[12] * px + vd[13] * py + vd[14];
    float dy = vd[15] * px + vd[16] * py + vd[17];
    float dz = vd[18] * px + vd[19] * py + vd[20];
    float dn = rsqrtf(dx * dx + dy * dy + dz * dz);
    dx *= dn; dy *= dn; dz *= dn;
    float rdx = Rc[0][0] * dx + Rc[0][1] * dy + Rc[0][2] * dz;
    float rdy = Rc[1][0] * dx + Rc[1][1] * dy + Rc[1][2] * dz;
    float rdz = Rc[2][0] * dx + Rc[2][1] * dy + Rc[2][2] * dz;
    float mex = vd[9]  + rdx * depth;
    float mey = vd[10] + rdy * depth;
    float mez = vd[11] + rdz * depth;

    // --- stores ---
    float* om  = out;
    float* os  = out + 3 * N;
    float* oc  = out + 6 * N;
    float* oq  = out + 15 * N;
    float* oo  = out + 19 * N;
    float* osh = out + 20 * N;

    om[3 * g + 0] = mex; om[3 * g + 1] = mey; om[3 * g + 2] = mez;
    os[3 * g + 0] = sc[0]; os[3 * g + 1] = sc[1]; os[3 * g + 2] = sc[2];
#pragma unroll
    for (int i = 0; i < 3; i++)
#pragma unroll
        for (int j = 0; j < 3; j++) oc[9 * g + i * 3 + j] = cov[i][j];
    ((float4*)oq)[g] = make_float4(qw, qx, qy, qz);   // 16B-aligned
    oo[g] = opac;

    // --- SH rotation, one channel at a time (25 in / 25 out live) ---
    float* shout = osh + 75 * g;
#pragma unroll
    for (int ch = 0; ch < 3; ch++) {
        float si[25];
        if (ch == 0) {            // elements 7..31
            si[0] = rec[7];
#pragma unroll
            for (int j = 0; j < 12; j++) { float2 v = rec2[4 + j];  si[1 + 2*j] = v.x; si[2 + 2*j] = v.y; }
        } else if (ch == 1) {     // elements 32..56
#pragma unroll
            for (int j = 0; j < 12; j++) { float2 v = rec2[16 + j]; si[2*j] = v.x; si[2*j + 1] = v.y; }
            si[24] = rec[56];
        } else {                  // elements 57..81
            si[0] = rec[57];
#pragma unroll
            for (int j = 0; j < 12; j++) { float2 v = rec2[29 + j]; si[1 + 2*j] = v.x; si[2 + 2*j] = v.y; }
        }
        float so[25];
        so[0] = si[0];
        apply_D<3>(vd + 22,  si + 1,  so + 1);
        apply_D<5>(vd + 31,  si + 4,  so + 4);
        apply_D<7>(vd + 56,  si + 9,  so + 9);
        apply_D<9>(vd + 105, si + 16, so + 16);
        float* o25 = shout + 25 * ch;
#pragma unroll
        for (int m = 0; m < 25; m++) o25[m] = so[m];
    }
}

extern "C" void kernel_launch(void* const* d_in, const int* in_sizes, int n_in,
                              void* d_out, int out_size, void* d_ws, size_t ws_size,
                              hipStream_t stream) {
    const float* pg   = (const float*)d_in[0];
    const float* pc   = (const float*)d_in[1];
    const float* ext  = (const float*)d_in[2];
    const float* intr = (const float*)d_in[3];
    const float* ops  = (const float*)d_in[4];
    const float* dep  = (const float*)d_in[5];
    const int*   ph   = (const int*)d_in[6];
    const int*   pw   = (const int*)d_in[7];

    int BV = in_sizes[2] / 16;               // extrinsics B*V*4*4
    long long N = (long long)in_sizes[4];    // opacities B*V*R
    int R = (int)(N / BV);

    float* vd = (float*)d_ws;
    setup_kernel<<<BV, 64, 0, stream>>>(ext, intr, ph, pw, vd);

    dim3 grid((R + 255) / 256, BV);
    adapter_kernel<<<grid, 256, 0, stream>>>(pg, pc, ops, dep, vd, (float*)d_out, R, N);
}

// Round 5
// 270.025 us; speedup vs baseline: 1.2461x; 1.2461x over previous
//
#include <hip/hip_runtime.h>

#define VSZ 192   // floats of per-view data in workspace (186 used, padded)

// ---------------- SH basis (degree 4, 25 components), float ----------------
__device__ __forceinline__ void sh_basis25(float x, float y, float z, float* Y) {
    float x2 = x * x, y2 = y * y, z2 = z * z;
    Y[0]  = 0.2820947918f;
    Y[1]  = 0.4886025119f * y;
    Y[2]  = 0.4886025119f * z;
    Y[3]  = 0.4886025119f * x;
    Y[4]  = 1.0925484306f * x * y;
    Y[5]  = 1.0925484306f * y * z;
    Y[6]  = 0.3153915653f * (3.0f * z2 - 1.0f);
    Y[7]  = 1.0925484306f * x * z;
    Y[8]  = 0.5462742153f * (x2 - y2);
    Y[9]  = 0.5900435899f * y * (3.0f * x2 - y2);
    Y[10] = 2.8906114426f * x * y * z;
    Y[11] = 0.4570457995f * y * (5.0f * z2 - 1.0f);
    Y[12] = 0.3731763326f * z * (5.0f * z2 - 3.0f);
    Y[13] = 0.4570457995f * x * (5.0f * z2 - 1.0f);
    Y[14] = 1.4453057213f * z * (x2 - y2);
    Y[15] = 0.5900435899f * x * (x2 - 3.0f * y2);
    Y[16] = 2.5033429418f * x * y * (x2 - y2);
    Y[17] = 1.7701307698f * y * z * (3.0f * x2 - y2);
    Y[18] = 0.9461746958f * x * y * (7.0f * z2 - 1.0f);
    Y[19] = 0.6690465436f * y * z * (7.0f * z2 - 3.0f);
    Y[20] = 0.1057855469f * (35.0f * z2 * z2 - 30.0f * z2 + 3.0f);
    Y[21] = 0.6690465436f * x * z * (7.0f * z2 - 3.0f);
    Y[22] = 0.4730873479f * (x2 - y2) * (7.0f * z2 - 1.0f);
    Y[23] = 1.7701307698f * x * z * (x2 - 3.0f * y2);
    Y[24] = 0.6258357354f * (x2 * x2 - 6.0f * x2 * y2 + y2 * y2);
}

// Per-view data layout (floats):
// [0:9) R_c2w  [9:12) cam_o  [12:21) Kinv  [21] scale_adj
// [22:31) D1   [31:56) D2    [56:105) D3   [105:186) D4
__global__ __launch_bounds__(64) void setup_kernel(
        const float* __restrict__ ext,
        const float* __restrict__ intr,
        const int* __restrict__ ph,
        const int* __restrict__ pw,
        float* __restrict__ vdg) {
    __shared__ float Bs[24][9];
    __shared__ float Yrs[24][9];
    __shared__ float normInv[24];

    int bv = blockIdx.x;
    int tid = threadIdx.x;
    const float* E = ext + bv * 16;
    const float* K = intr + bv * 9;
    float* o = vdg + bv * VSZ;

    const float z0 = 0.5f, r0 = 0.8660254037844386f;  // sqrt(3)/2
    const float TWO_PI = 6.283185307179586f;

    if (tid < 24) {
        int l, base;
        if      (tid < 3)  { l = 1; base = 0;  }
        else if (tid < 8)  { l = 2; base = 3;  }
        else if (tid < 15) { l = 3; base = 8;  }
        else               { l = 4; base = 15; }
        int n  = 2 * l + 1;
        int si = tid - base;
        int lo = l * l;
        float phs = 0.4f + TWO_PI * (float)si / (float)n;
        float sx = r0 * cosf(phs), sy = r0 * sinf(phs), sz = z0;
        float Y[25];
        sh_basis25(sx, sy, sz, Y);
        for (int k = 0; k < n; k++) Bs[tid][k] = Y[lo + k];
        float dx = E[0] * sx + E[1] * sy + E[2]  * sz;
        float dy = E[4] * sx + E[5] * sy + E[6]  * sz;
        float dz = E[8] * sx + E[9] * sy + E[10] * sz;
        sh_basis25(dx, dy, dz, Y);
        for (int k = 0; k < n; k++) Yrs[tid][k] = Y[lo + k];
    }
    __syncthreads();

    if (tid < 24) {
        int l, base;
        if      (tid < 3)  { l = 1; base = 0;  }
        else if (tid < 8)  { l = 2; base = 3;  }
        else if (tid < 15) { l = 3; base = 8;  }
        else               { l = 4; base = 15; }
        int n = 2 * l + 1;
        int m = tid - base;
        float acc = 0.f;
        for (int s = 0; s < n; s++) { float v = Bs[base + s][m]; acc += v * v; }
        normInv[tid] = 1.0f / acc;
    }
    __syncthreads();

    const int dofs[5] = {0, 22, 31, 56, 105};
    for (int e = tid; e < 164; e += 64) {
        int l, ebase, sbase;
        if      (e < 9)  { l = 1; ebase = 0;  sbase = 0;  }
        else if (e < 34) { l = 2; ebase = 9;  sbase = 3;  }
        else if (e < 83) { l = 3; ebase = 34; sbase = 8;  }
        else             { l = 4; ebase = 83; sbase = 15; }
        int n = 2 * l + 1;
        int el = e - ebase;
        int m = el / n, k = el % n;
        float acc = 0.f;
        for (int s = 0; s < n; s++) acc += Yrs[sbase + s][k] * Bs[sbase + s][m];
        o[dofs[l] + m * n + k] = acc * normInv[sbase + m];
    }

    if (tid == 0) {
        float Rw2c[3][3], Rc2w[3][3], t[3];
        for (int i = 0; i < 3; i++) {
            for (int j = 0; j < 3; j++) Rw2c[i][j] = E[i * 4 + j];
            t[i] = E[i * 4 + 3];
        }
        for (int i = 0; i < 3; i++)
            for (int j = 0; j < 3; j++) Rc2w[i][j] = Rw2c[j][i];
        for (int i = 0; i < 3; i++)
            for (int j = 0; j < 3; j++) o[i * 3 + j] = Rc2w[i][j];
        for (int i = 0; i < 3; i++) {
            float s = 0.f;
            for (int j = 0; j < 3; j++) s += Rc2w[i][j] * t[j];
            o[9 + i] = -s;
        }
        float a = K[0], b = K[1], c = K[2], d = K[3], e = K[4], f = K[5],
              g = K[6], h = K[7], ii = K[8];
        float det = a * (e * ii - f * h) - b * (d * ii - f * g) + c * (d * h - e * g);
        float id = 1.0f / det;
        o[12 + 0] = (e * ii - f * h) * id; o[12 + 1] = (c * h - b * ii) * id; o[12 + 2] = (b * f - c * e) * id;
        o[12 + 3] = (f * g - d * ii) * id; o[12 + 4] = (a * ii - c * g) * id; o[12 + 5] = (c * d - a * f) * id;
        o[12 + 6] = (d * h - e * g) * id; o[12 + 7] = (b * g - a * h) * id; o[12 + 8] = (a * e - b * d) * id;
        float det2 = a * e - b * d;
        float i00 = e / det2, i01 = -b / det2, i10 = -d / det2, i11 = a / det2;
        float ps0 = 1.0f / (float)(*pw), ps1 = 1.0f / (float)(*ph);
        o[21] = 0.1f * ((i00 + i10) * ps0 + (i01 + i11) * ps1);
    }
}

template <int NB>
__device__ __forceinline__ void apply_D(const float* __restrict__ D,
                                        const float* __restrict__ si,
                                        float* __restrict__ so) {
#pragma unroll
    for (int m = 0; m < NB; m++) {
        float acc = 0.f;
#pragma unroll
        for (int k = 0; k < NB; k++) acc += D[m * NB + k] * si[k];
        so[m] = acc;
    }
}

// One thread per gaussian. Each record region is consumed IMMEDIATELY after
// loading (reuse distance ~0), and all 75 SH outputs accumulate in registers
// and are stored in ONE burst so every output cache line is fully covered by
// temporally-adjacent stores (no partial-line writeback amplification).
__global__ __launch_bounds__(256, 3) void adapter_kernel(
    const float* __restrict__ pg, const float* __restrict__ pc,
    const float* __restrict__ ops, const float* __restrict__ deps,
    const float* __restrict__ vdg, float* __restrict__ out,
    int R, long long N)
{
    __shared__ float vd[VSZ];
    int bv = blockIdx.y;
    for (int i = threadIdx.x; i < 186; i += 256) vd[i] = vdg[bv * VSZ + i];
    __syncthreads();

    int r = blockIdx.x * 256 + threadIdx.x;
    if (r >= R) return;
    long long g = (long long)bv * R + r;

    const float*  rec  = pg + g * 82;
    const float2* rec2 = (const float2*)rec;

    float depth = deps[g];
    float opac  = ops[g];
    float2 pxy  = ((const float2*)pc)[g];
    float px = pxy.x, py = pxy.y;

    // ---- geometry inputs (rec[0..6]) ----
    float2 v01 = rec2[0], v23 = rec2[1], v45 = rec2[2];
    float  v6  = rec[6];

    float sadj = vd[21];
    float sraw[3] = {v01.x, v01.y, v23.x};
    float sc[3];
#pragma unroll
    for (int i = 0; i < 3; i++) {
        float sg = 1.0f / (1.0f + expf(-sraw[i]));
        sc[i] = (0.01f + 99.99f * sg) * depth * sadj;
    }

    float qw = v23.y, qx = v45.x, qy = v45.y, qz = v6;
    float qn = rsqrtf(qw * qw + qx * qx + qy * qy + qz * qz);
    qw *= qn; qx *= qn; qy *= qn; qz *= qn;
    float Rq[3][3];
    Rq[0][0] = 1.f - 2.f * (qy * qy + qz * qz);
    Rq[0][1] = 2.f * (qx * qy - qw * qz);
    Rq[0][2] = 2.f * (qx * qz + qw * qy);
    Rq[1][0] = 2.f * (qx * qy + qw * qz);
    Rq[1][1] = 1.f - 2.f * (qx * qx + qz * qz);
    Rq[1][2] = 2.f * (qy * qz - qw * qx);
    Rq[2][0] = 2.f * (qx * qz - qw * qy);
    Rq[2][1] = 2.f * (qy * qz + qw * qx);
    Rq[2][2] = 1.f - 2.f * (qx * qx + qy * qy);

    float Rc[3][3];
#pragma unroll
    for (int i = 0; i < 3; i++)
#pragma unroll
        for (int j = 0; j < 3; j++) Rc[i][j] = vd[i * 3 + j];

    float A[3][3];
#pragma unroll
    for (int i = 0; i < 3; i++)
#pragma unroll
        for (int k = 0; k < 3; k++)
            A[i][k] = Rc[i][0] * Rq[0][k] + Rc[i][1] * Rq[1][k] + Rc[i][2] * Rq[2][k];
    float s2[3] = {sc[0] * sc[0], sc[1] * sc[1], sc[2] * sc[2]};
    float cov[3][3];
#pragma unroll
    for (int i = 0; i < 3; i++)
#pragma unroll
        for (int j = 0; j < 3; j++)
            cov[i][j] = A[i][0] * s2[0] * A[j][0] + A[i][1] * s2[1] * A[j][1] + A[i][2] * s2[2] * A[j][2];

    float dx = vd[12] * px + vd[13] * py + vd[14];
    float dy = vd[15] * px + vd[16] * py + vd[17];
    float dz = vd[18] * px + vd[19] * py + vd[20];
    float dn = rsqrtf(dx * dx + dy * dy + dz * dz);
    dx *= dn; dy *= dn; dz *= dn;
    float rdx = Rc[0][0] * dx + Rc[0][1] * dy + Rc[0][2] * dz;
    float rdy = Rc[1][0] * dx + Rc[1][1] * dy + Rc[1][2] * dz;
    float rdz = Rc[2][0] * dx + Rc[2][1] * dy + Rc[2][2] * dz;
    float mex = vd[9]  + rdx * depth;
    float mey = vd[10] + rdy * depth;
    float mez = vd[11] + rdz * depth;

    // ---- geometry stores (dense per-wave regions, immediate) ----
    float* om  = out;
    float* os  = out + 3 * N;
    float* oc  = out + 6 * N;
    float* oq  = out + 15 * N;
    float* oo  = out + 19 * N;
    float* osh = out + 20 * N;

    om[3 * g + 0] = mex; om[3 * g + 1] = mey; om[3 * g + 2] = mez;
    os[3 * g + 0] = sc[0]; os[3 * g + 1] = sc[1]; os[3 * g + 2] = sc[2];
#pragma unroll
    for (int i = 0; i < 3; i++)
#pragma unroll
        for (int j = 0; j < 3; j++) oc[9 * g + i * 3 + j] = cov[i][j];
    ((float4*)oq)[g] = make_float4(qw, qx, qy, qz);
    oo[g] = opac;

    // ---- SH: load each channel right before transforming it; accumulate all
    //      75 outputs in registers (static indices only). ----
    float shreg[75];
#pragma unroll
    for (int ch = 0; ch < 3; ch++) {
        float si[25];
        if (ch == 0) {            // rec[7..31]
            si[0] = rec[7];
#pragma unroll
            for (int j = 0; j < 12; j++) { float2 v = rec2[4 + j];  si[1 + 2*j] = v.x; si[2 + 2*j] = v.y; }
        } else if (ch == 1) {     // rec[32..56]
#pragma unroll
            for (int j = 0; j < 12; j++) { float2 v = rec2[16 + j]; si[2*j] = v.x; si[2*j + 1] = v.y; }
            si[24] = rec[56];
        } else {                  // rec[57..81]
            si[0] = rec[57];
#pragma unroll
            for (int j = 0; j < 12; j++) { float2 v = rec2[29 + j]; si[1 + 2*j] = v.x; si[2 + 2*j] = v.y; }
        }
        float* so = shreg + 25 * ch;
        so[0] = si[0];
        apply_D<3>(vd + 22,  si + 1,  so + 1);
        apply_D<5>(vd + 31,  si + 4,  so + 4);
        apply_D<7>(vd + 56,  si + 9,  so + 9);
        apply_D<9>(vd + 105, si + 16, so + 16);
    }

    // ---- single SH store burst: 75 consecutive floats per thread ----
    float* shout = osh + 75 * g;
#pragma unroll
    for (int m = 0; m < 75; m++) shout[m] = shreg[m];
}

extern "C" void kernel_launch(void* const* d_in, const int* in_sizes, int n_in,
                              void* d_out, int out_size, void* d_ws, size_t ws_size,
                              hipStream_t stream) {
    const float* pg   = (const float*)d_in[0];
    const float* pc   = (const float*)d_in[1];
    const float* ext  = (const float*)d_in[2];
    const float* intr = (const float*)d_in[3];
    const float* ops  = (const float*)d_in[4];
    const float* dep  = (const float*)d_in[5];
    const int*   ph   = (const int*)d_in[6];
    const int*   pw   = (const int*)d_in[7];

    int BV = in_sizes[2] / 16;               // extrinsics B*V*4*4
    long long N = (long long)in_sizes[4];    // opacities B*V*R
    int R = (int)(N / BV);

    float* vd = (float*)d_ws;
    setup_kernel<<<BV, 64, 0, stream>>>(ext, intr, ph, pw, vd);

    dim3 grid((R + 255) / 256, BV);
    adapter_kernel<<<grid, 256, 0, stream>>>(pg, pc, ops, dep, vd, (float*)d_out, R, N);
}

// Round 6
// 92.916 us; speedup vs baseline: 3.6214x; 2.9061x over previous
//
#include <hip/hip_runtime.h>

#define VSZ  192   // floats of per-view data (186 used, padded)
#define TILE 64    // records per block
#define ROWW 98    // padded LDS row width (95 outputs / 82 inputs fit; 98 even, bank-stride 2)
#define NTHR 256

// ---------------- SH basis (degree 4, 25 components), float ----------------
__device__ __forceinline__ void sh_basis25(float x, float y, float z, float* Y) {
    float x2 = x * x, y2 = y * y, z2 = z * z;
    Y[0]  = 0.2820947918f;
    Y[1]  = 0.4886025119f * y;
    Y[2]  = 0.4886025119f * z;
    Y[3]  = 0.4886025119f * x;
    Y[4]  = 1.0925484306f * x * y;
    Y[5]  = 1.0925484306f * y * z;
    Y[6]  = 0.3153915653f * (3.0f * z2 - 1.0f);
    Y[7]  = 1.0925484306f * x * z;
    Y[8]  = 0.5462742153f * (x2 - y2);
    Y[9]  = 0.5900435899f * y * (3.0f * x2 - y2);
    Y[10] = 2.8906114426f * x * y * z;
    Y[11] = 0.4570457995f * y * (5.0f * z2 - 1.0f);
    Y[12] = 0.3731763326f * z * (5.0f * z2 - 3.0f);
    Y[13] = 0.4570457995f * x * (5.0f * z2 - 1.0f);
    Y[14] = 1.4453057213f * z * (x2 - y2);
    Y[15] = 0.5900435899f * x * (x2 - 3.0f * y2);
    Y[16] = 2.5033429418f * x * y * (x2 - y2);
    Y[17] = 1.7701307698f * y * z * (3.0f * x2 - y2);
    Y[18] = 0.9461746958f * x * y * (7.0f * z2 - 1.0f);
    Y[19] = 0.6690465436f * y * z * (7.0f * z2 - 3.0f);
    Y[20] = 0.1057855469f * (35.0f * z2 * z2 - 30.0f * z2 + 3.0f);
    Y[21] = 0.6690465436f * x * z * (7.0f * z2 - 3.0f);
    Y[22] = 0.4730873479f * (x2 - y2) * (7.0f * z2 - 1.0f);
    Y[23] = 1.7701307698f * x * z * (x2 - 3.0f * y2);
    Y[24] = 0.6258357354f * (x2 * x2 - 6.0f * x2 * y2 + y2 * y2);
}

// Per-view data layout (floats):
// [0:9) R_c2w  [9:12) cam_o  [12:21) Kinv  [21] scale_adj
// [22:31) D1   [31:56) D2    [56:105) D3   [105:186) D4
__global__ __launch_bounds__(64) void setup_kernel(
        const float* __restrict__ ext,
        const float* __restrict__ intr,
        const int* __restrict__ ph,
        const int* __restrict__ pw,
        float* __restrict__ vdg) {
    __shared__ float Bs[24][9];
    __shared__ float Yrs[24][9];
    __shared__ float normInv[24];

    int bv = blockIdx.x;
    int tid = threadIdx.x;
    const float* E = ext + bv * 16;
    const float* K = intr + bv * 9;
    float* o = vdg + bv * VSZ;

    const float z0 = 0.5f, r0 = 0.8660254037844386f;  // sqrt(3)/2
    const float TWO_PI = 6.283185307179586f;

    if (tid < 24) {
        int l, base;
        if      (tid < 3)  { l = 1; base = 0;  }
        else if (tid < 8)  { l = 2; base = 3;  }
        else if (tid < 15) { l = 3; base = 8;  }
        else               { l = 4; base = 15; }
        int n  = 2 * l + 1;
        int si = tid - base;
        int lo = l * l;
        float phs = 0.4f + TWO_PI * (float)si / (float)n;
        float sx = r0 * cosf(phs), sy = r0 * sinf(phs), sz = z0;
        float Y[25];
        sh_basis25(sx, sy, sz, Y);
        for (int k = 0; k < n; k++) Bs[tid][k] = Y[lo + k];
        float dx = E[0] * sx + E[1] * sy + E[2]  * sz;
        float dy = E[4] * sx + E[5] * sy + E[6]  * sz;
        float dz = E[8] * sx + E[9] * sy + E[10] * sz;
        sh_basis25(dx, dy, dz, Y);
        for (int k = 0; k < n; k++) Yrs[tid][k] = Y[lo + k];
    }
    __syncthreads();

    if (tid < 24) {
        int l, base;
        if      (tid < 3)  { l = 1; base = 0;  }
        else if (tid < 8)  { l = 2; base = 3;  }
        else if (tid < 15) { l = 3; base = 8;  }
        else               { l = 4; base = 15; }
        int n = 2 * l + 1;
        int m = tid - base;
        float acc = 0.f;
        for (int s = 0; s < n; s++) { float v = Bs[base + s][m]; acc += v * v; }
        normInv[tid] = 1.0f / acc;
    }
    __syncthreads();

    const int dofs[5] = {0, 22, 31, 56, 105};
    for (int e = tid; e < 164; e += 64) {
        int l, ebase, sbase;
        if      (e < 9)  { l = 1; ebase = 0;  sbase = 0;  }
        else if (e < 34) { l = 2; ebase = 9;  sbase = 3;  }
        else if (e < 83) { l = 3; ebase = 34; sbase = 8;  }
        else             { l = 4; ebase = 83; sbase = 15; }
        int n = 2 * l + 1;
        int el = e - ebase;
        int m = el / n, k = el % n;
        float acc = 0.f;
        for (int s = 0; s < n; s++) acc += Yrs[sbase + s][k] * Bs[sbase + s][m];
        o[dofs[l] + m * n + k] = acc * normInv[sbase + m];
    }

    if (tid == 0) {
        float Rw2c[3][3], Rc2w[3][3], t[3];
        for (int i = 0; i < 3; i++) {
            for (int j = 0; j < 3; j++) Rw2c[i][j] = E[i * 4 + j];
            t[i] = E[i * 4 + 3];
        }
        for (int i = 0; i < 3; i++)
            for (int j = 0; j < 3; j++) Rc2w[i][j] = Rw2c[j][i];
        for (int i = 0; i < 3; i++)
            for (int j = 0; j < 3; j++) o[i * 3 + j] = Rc2w[i][j];
        for (int i = 0; i < 3; i++) {
            float s = 0.f;
            for (int j = 0; j < 3; j++) s += Rc2w[i][j] * t[j];
            o[9 + i] = -s;
        }
        float a = K[0], b = K[1], c = K[2], d = K[3], e = K[4], f = K[5],
              g = K[6], h = K[7], ii = K[8];
        float det = a * (e * ii - f * h) - b * (d * ii - f * g) + c * (d * h - e * g);
        float id = 1.0f / det;
        o[12 + 0] = (e * ii - f * h) * id; o[12 + 1] = (c * h - b * ii) * id; o[12 + 2] = (b * f - c * e) * id;
        o[12 + 3] = (f * g - d * ii) * id; o[12 + 4] = (a * ii - c * g) * id; o[12 + 5] = (c * d - a * f) * id;
        o[12 + 6] = (d * h - e * g) * id; o[12 + 7] = (b * g - a * h) * id; o[12 + 8] = (a * e - b * d) * id;
        float det2 = a * e - b * d;
        float i00 = e / det2, i01 = -b / det2, i10 = -d / det2, i11 = a / det2;
        float ps0 = 1.0f / (float)(*pw), ps1 = 1.0f / (float)(*ph);
        o[21] = 0.1f * ((i00 + i10) * ps0 + (i01 + i11) * ps1);
    }
}

template <int NB>
__device__ __forceinline__ void apply_D(const float* __restrict__ D,
                                        const float* __restrict__ si,
                                        float* __restrict__ so) {
#pragma unroll
    for (int m = 0; m < NB; m++) {
        float acc = 0.f;
#pragma unroll
        for (int k = 0; k < NB; k++) acc += D[m * NB + k] * si[k];
        so[m] = acc;
    }
}

template <int W>
__device__ __forceinline__ void copy_sec(const float* __restrict__ lds,
                                         float* __restrict__ dst,
                                         int cb, int cnt) {
    for (int e = threadIdx.x; e < cnt * W; e += NTHR) {
        int r = e / W, c = e - r * W;
        dst[e] = lds[r * ROWW + cb + c];
    }
}

// Block = 256 threads, 64 records. Wave role-split: wave0 = geometry,
// waves1-3 = one SH channel each. All global traffic is staged through an
// LDS tile so every global load/store instruction is lane-contiguous
// (full-cache-line coverage per instruction -> no RFO / partial-writeback
// amplification). Outputs are written back into the same tile rows in
// OUTPUT layout: [means3|scales3|cov9|quats4|op1|sh75] = 95 cols.
__global__ __launch_bounds__(NTHR, 6) void adapter_kernel(
    const float* __restrict__ pg, const float* __restrict__ pc,
    const float* __restrict__ ops, const float* __restrict__ deps,
    const float* __restrict__ vdg, float* __restrict__ out,
    int R, long long N)
{
    __shared__ float tile[TILE * ROWW];
    __shared__ float vd[VSZ];

    int bv = blockIdx.y;
    long long tilebase = (long long)bv * R + (long long)blockIdx.x * TILE;
    int cnt = R - blockIdx.x * TILE;
    if (cnt > TILE) cnt = TILE;

    // ---- stage per-view constants + input tile (coalesced) ----
    for (int i = threadIdx.x; i < 186; i += NTHR) vd[i] = vdg[bv * VSZ + i];

    const float* src = pg + tilebase * 82;
    if (cnt == TILE && ((tilebase & 1) == 0)) {
        const float4* s4 = (const float4*)src;          // tilebase*328 % 16 == 0
        for (int e4 = threadIdx.x; e4 < TILE * 82 / 4; e4 += NTHR) {
            float4 v = s4[e4];
            int f = 4 * e4;
#pragma unroll
            for (int j = 0; j < 4; j++) {
                int ff = f + j;
                int rr = ff / 82, cc = ff - rr * 82;
                tile[rr * ROWW + cc] = (&v.x)[j];
            }
        }
    } else {
        for (int ff = threadIdx.x; ff < cnt * 82; ff += NTHR) {
            int rr = ff / 82, cc = ff - rr * 82;
            tile[rr * ROWW + cc] = src[ff];
        }
    }
    __syncthreads();

    // ---- read phase: each wave pulls its slice into registers ----
    int rec = threadIdx.x & 63;
    int sub = threadIdx.x >> 6;          // wave-uniform role
    bool active = rec < cnt;
    long long g = tilebase + rec;
    float* row = tile + rec * ROWW;

    float gin[7];                         // sub0: raw geometry inputs
    float depth = 0.f, opac = 0.f, px = 0.f, py = 0.f;
    float si[25];                         // sub1..3: SH channel input

    if (sub == 0) {
        if (active) {
#pragma unroll
            for (int i = 0; i < 7; i++) gin[i] = row[i];
            depth = deps[g];
            opac  = ops[g];
            float2 pxy = ((const float2*)pc)[g];
            px = pxy.x; py = pxy.y;
        }
    } else {
        if (active) {
            int cb = 7 + 25 * (sub - 1);
#pragma unroll
            for (int m = 0; m < 25; m++) si[m] = row[cb + m];
        }
    }
    __syncthreads();

    // ---- compute + write back into tile rows (output layout) ----
    if (sub == 0) {
        if (active) {
            float sadj = vd[21];
            float sc[3];
#pragma unroll
            for (int i = 0; i < 3; i++) {
                float sg = 1.0f / (1.0f + expf(-gin[i]));
                sc[i] = (0.01f + 99.99f * sg) * depth * sadj;
            }
            float qw = gin[3], qx = gin[4], qy = gin[5], qz = gin[6];
            float qn = rsqrtf(qw * qw + qx * qx + qy * qy + qz * qz);
            qw *= qn; qx *= qn; qy *= qn; qz *= qn;
            float Rq[3][3];
            Rq[0][0] = 1.f - 2.f * (qy * qy + qz * qz);
            Rq[0][1] = 2.f * (qx * qy - qw * qz);
            Rq[0][2] = 2.f * (qx * qz + qw * qy);
            Rq[1][0] = 2.f * (qx * qy + qw * qz);
            Rq[1][1] = 1.f - 2.f * (qx * qx + qz * qz);
            Rq[1][2] = 2.f * (qy * qz - qw * qx);
            Rq[2][0] = 2.f * (qx * qz - qw * qy);
            Rq[2][1] = 2.f * (qy * qz + qw * qx);
            Rq[2][2] = 1.f - 2.f * (qx * qx + qy * qy);

            float Rc[3][3];
#pragma unroll
            for (int i = 0; i < 3; i++)
#pragma unroll
                for (int j = 0; j < 3; j++) Rc[i][j] = vd[i * 3 + j];

            float A[3][3];
#pragma unroll
            for (int i = 0; i < 3; i++)
#pragma unroll
                for (int k = 0; k < 3; k++)
                    A[i][k] = Rc[i][0] * Rq[0][k] + Rc[i][1] * Rq[1][k] + Rc[i][2] * Rq[2][k];
            float s2[3] = {sc[0] * sc[0], sc[1] * sc[1], sc[2] * sc[2]};

            float dx = vd[12] * px + vd[13] * py + vd[14];
            float dy = vd[15] * px + vd[16] * py + vd[17];
            float dz = vd[18] * px + vd[19] * py + vd[20];
            float dn = rsqrtf(dx * dx + dy * dy + dz * dz);
            dx *= dn; dy *= dn; dz *= dn;
            float rdx = Rc[0][0] * dx + Rc[0][1] * dy + Rc[0][2] * dz;
            float rdy = Rc[1][0] * dx + Rc[1][1] * dy + Rc[1][2] * dz;
            float rdz = Rc[2][0] * dx + Rc[2][1] * dy + Rc[2][2] * dz;

            // output layout: [0:3) means [3:6) scales [6:15) cov [15:19) quats [19] op
            row[0] = vd[9]  + rdx * depth;
            row[1] = vd[10] + rdy * depth;
            row[2] = vd[11] + rdz * depth;
            row[3] = sc[0]; row[4] = sc[1]; row[5] = sc[2];
#pragma unroll
            for (int i = 0; i < 3; i++)
#pragma unroll
                for (int j = 0; j < 3; j++)
                    row[6 + i * 3 + j] = A[i][0] * s2[0] * A[j][0] + A[i][1] * s2[1] * A[j][1] + A[i][2] * s2[2] * A[j][2];
            row[15] = qw; row[16] = qx; row[17] = qy; row[18] = qz;
            row[19] = opac;
        }
    } else {
        if (active) {
            float so[25];
            so[0] = si[0];
            apply_D<3>(vd + 22,  si + 1,  so + 1);
            apply_D<5>(vd + 31,  si + 4,  so + 4);
            apply_D<7>(vd + 56,  si + 9,  so + 9);
            apply_D<9>(vd + 105, si + 16, so + 16);
            int ob = 20 + 25 * (sub - 1);
#pragma unroll
            for (int m = 0; m < 25; m++) row[ob + m] = so[m];
        }
    }
    __syncthreads();

    // ---- coalesced copy-out per output section ----
    copy_sec<3>(tile,  out +           3 * tilebase, 0,  cnt);   // means
    copy_sec<3>(tile,  out +  3 * N +  3 * tilebase, 3,  cnt);   // scales
    copy_sec<9>(tile,  out +  6 * N +  9 * tilebase, 6,  cnt);   // cov
    copy_sec<4>(tile,  out + 15 * N +  4 * tilebase, 15, cnt);   // quats
    copy_sec<1>(tile,  out + 19 * N +      tilebase, 19, cnt);   // op
    copy_sec<75>(tile, out + 20 * N + 75 * tilebase, 20, cnt);   // sh
}

extern "C" void kernel_launch(void* const* d_in, const int* in_sizes, int n_in,
                              void* d_out, int out_size, void* d_ws, size_t ws_size,
                              hipStream_t stream) {
    const float* pg   = (const float*)d_in[0];
    const float* pc   = (const float*)d_in[1];
    const float* ext  = (const float*)d_in[2];
    const float* intr = (const float*)d_in[3];
    const float* ops  = (const float*)d_in[4];
    const float* dep  = (const float*)d_in[5];
    const int*   ph   = (const int*)d_in[6];
    const int*   pw   = (const int*)d_in[7];

    int BV = in_sizes[2] / 16;               // extrinsics B*V*4*4
    long long N = (long long)in_sizes[4];    // opacities B*V*R
    int R = (int)(N / BV);

    float* vd = (float*)d_ws;
    setup_kernel<<<BV, 64, 0, stream>>>(ext, intr, ph, pw, vd);

    dim3 grid((R + TILE - 1) / TILE, BV);
    adapter_kernel<<<grid, NTHR, 0, stream>>>(pg, pc, ops, dep, vd, (float*)d_out, R, N);
}